// Round 19
// baseline (567.123 us; speedup 1.0000x reference)
//
#include <hip/hip_runtime.h>
#include <hip/hip_bf16.h>
#include <math.h>

#define S_ORIG 4095
#define LPAD   4096
#define NHEADS 16
#define DH     64
#define NLM    128
#define BHT    32        // B * NHEADS
#define HIDDEN 1024
#define QKSCALE 0.35355339059327373f   // 1 / 64^0.25

typedef unsigned short u16;
typedef short s16x8 __attribute__((ext_vector_type(8)));
typedef float f32x4 __attribute__((ext_vector_type(4)));
typedef float f32x16 __attribute__((ext_vector_type(16)));

// XOR-swizzled LDS indices (spread row-stride power-of-2 across banks)
#define IDX64(r, c)  ((r) * 64 + ((c) ^ (((r) & 7) << 3)))
#define IDX128(r, c) ((r) * 128 + ((c) ^ (((r) & 7) << 3)))

// ---------------------------------------------------------------------------
__device__ inline void split2(float x, u16& h, u16& l) {
    __hip_bfloat16 bh = __float2bfloat16(x);
    float fh = __bfloat162float(bh);
    __hip_bfloat16 bl = __float2bfloat16(x - fh);
    h = *(u16*)&bh;
    l = *(u16*)&bl;
}

__device__ inline float bf16f(u16 b) {
    unsigned u = ((unsigned)b) << 16;
    return *(float*)&u;
}

// X (B,4095,1024) fp32 -> XH, XL (8192,1024) bf16-bits, pad row (l==4095) zero.
__global__ __launch_bounds__(256) void k_split_x(const float* __restrict__ X,
                                                 u16* __restrict__ XH,
                                                 u16* __restrict__ XL) {
    int idx = blockIdx.x * 256 + threadIdx.x;      // one thread = 4 elems
    int gr = idx >> 8;                             // row 0..8191
    int c4 = (idx & 255) * 4;
    int b = gr >> 12, l = gr & (LPAD - 1);
    float4 v = make_float4(0.f, 0.f, 0.f, 0.f);
    if (l < S_ORIG) v = *(const float4*)(X + ((size_t)b * S_ORIG + l) * HIDDEN + c4);
    ushort4 h4, l4;
    split2(v.x, h4.x, l4.x); split2(v.y, h4.y, l4.y);
    split2(v.z, h4.z, l4.z); split2(v.w, h4.w, l4.w);
    size_t o = (size_t)gr * HIDDEN + c4;
    *(ushort4*)(XH + o) = h4;
    *(ushort4*)(XL + o) = l4;
}

// All four weights split in one launch. grid (1024, 4).
__global__ __launch_bounds__(256) void k_split_w4(
    const float* __restrict__ W0, const float* __restrict__ W1,
    const float* __restrict__ W2, const float* __restrict__ W3,
    u16* __restrict__ H0, u16* __restrict__ L0,
    u16* __restrict__ H1, u16* __restrict__ L1,
    u16* __restrict__ H2, u16* __restrict__ L2,
    u16* __restrict__ H3, u16* __restrict__ L3) {
    int ws = blockIdx.y;
    const float* W = (ws == 0) ? W0 : (ws == 1) ? W1 : (ws == 2) ? W2 : W3;
    u16* H = (ws == 0) ? H0 : (ws == 1) ? H1 : (ws == 2) ? H2 : H3;
    u16* L = (ws == 0) ? L0 : (ws == 1) ? L1 : (ws == 2) ? L2 : L3;
    int idx = blockIdx.x * 256 + threadIdx.x;
    size_t o = (size_t)idx * 4;
    float4 v = *(const float4*)(W + o);
    ushort4 h4, l4;
    split2(v.x, h4.x, l4.x); split2(v.y, h4.y, l4.y);
    split2(v.z, h4.z, l4.z); split2(v.w, h4.w, l4.w);
    *(ushort4*)(H + o) = h4;
    *(ushort4*)(L + o) = l4;
}

// ---------------------------------------------------------------------------
// Split-bf16 MFMA GEMM, BK=64, 64 KB LDS, 32x32x16 MFMA (higher pipe ceiling,
// half the instruction count of the 16x16x32 version).
// Wave tile 64x64 = 2x2 fragments of 32x32. A/B operand layout: row=lane&31,
// k=(lane>>5)*8+e. C/D layout (HW-verified m74/m101): col=lane&31,
// row=(reg&3)+8*(reg>>2)+4*(lane>>5).
// mode 0: fused QKV, outputs bf16 PAIRS; blockIdx.y: seg=y>>3, col0=(y&7)*128.
// mode 1: final projection (B0 slot), fp32 out rows l < 4095, grid y = 8.
// ---------------------------------------------------------------------------
__global__ __launch_bounds__(256) void k_gemm_bf16(
    const u16* __restrict__ AH, const u16* __restrict__ AL,
    const u16* __restrict__ B0H, const u16* __restrict__ B0L,
    const u16* __restrict__ B1H, const u16* __restrict__ B1L,
    const u16* __restrict__ B2H, const u16* __restrict__ B2L,
    const float* __restrict__ bias0, const float* __restrict__ bias1,
    const float* __restrict__ bias2, const float* __restrict__ mask,
    u16* __restrict__ QPH, u16* __restrict__ QPL,
    u16* __restrict__ KPH, u16* __restrict__ KPL,
    u16* __restrict__ VPH, u16* __restrict__ VPL,
    float* __restrict__ outF, int mode)
{
    __shared__ u16 Ah_lds[128 * 64];
    __shared__ u16 Al_lds[128 * 64];
    __shared__ u16 Bh_lds[128 * 64];
    __shared__ u16 Bl_lds[128 * 64];
    int tid = threadIdx.x;
    int seg = (mode == 0) ? (blockIdx.y >> 3) : 0;
    int row0 = blockIdx.x * 128;
    int col0 = (mode == 0) ? ((blockIdx.y & 7) * 128) : (blockIdx.y * 128);
    const u16* BH = (seg == 0) ? B0H : (seg == 1) ? B1H : B2H;
    const u16* BL = (seg == 0) ? B0L : (seg == 1) ? B1L : B2L;
    const float* bias = (seg == 0) ? bias0 : (seg == 1) ? bias1 : bias2;
    u16* PH = (seg == 0) ? QPH : (seg == 1) ? KPH : VPH;
    u16* PL = (seg == 0) ? QPL : (seg == 1) ? KPL : VPL;

    int lane = tid & 63, wv = tid >> 6;
    int wr = (wv >> 1) * 64, wc = (wv & 1) * 64;
    int lr32 = lane & 31, lk2 = lane >> 5;         // frag row, k-half (0/1)
    int sr8 = tid >> 3, sc = tid & 7;              // staging row base, chunk 0..7

    f32x16 acc[2][2] = {};

    for (int kt = 0; kt < 1024; kt += 64) {
        #pragma unroll
        for (int h = 0; h < 4; ++h) {
            int r = sr8 + h * 32;
            int csrc = (sc ^ (r & 7)) * 8;         // inverse-swizzled source col
            size_t ga = (size_t)(row0 + r) * HIDDEN + kt + csrc;
            size_t gb = (size_t)(col0 + r) * HIDDEN + kt + csrc;
            int ldst = r * 64 + sc * 8;            // linear dest (lane*16B)
            __builtin_amdgcn_global_load_lds(
                (const __attribute__((address_space(1))) void*)(AH + ga),
                (__attribute__((address_space(3))) void*)(&Ah_lds[ldst]), 16, 0, 0);
            __builtin_amdgcn_global_load_lds(
                (const __attribute__((address_space(1))) void*)(AL + ga),
                (__attribute__((address_space(3))) void*)(&Al_lds[ldst]), 16, 0, 0);
            __builtin_amdgcn_global_load_lds(
                (const __attribute__((address_space(1))) void*)(BH + gb),
                (__attribute__((address_space(3))) void*)(&Bh_lds[ldst]), 16, 0, 0);
            __builtin_amdgcn_global_load_lds(
                (const __attribute__((address_space(1))) void*)(BL + gb),
                (__attribute__((address_space(3))) void*)(&Bl_lds[ldst]), 16, 0, 0);
        }
        __syncthreads();
        #pragma unroll
        for (int kc = 0; kc < 4; ++kc) {           // 4 K-sub-steps of 16
            s16x8 ah[2], al[2], bh4[2], bl4[2];
            #pragma unroll
            for (int i = 0; i < 2; ++i) {
                int ra = wr + i * 32 + lr32;
                int rb = wc + i * 32 + lr32;
                int ca = ((kc * 2 + lk2) ^ (ra & 7)) * 8;   // swizzled read col
                int cb = ((kc * 2 + lk2) ^ (rb & 7)) * 8;
                ah[i]  = *(const s16x8*)&Ah_lds[ra * 64 + ca];
                al[i]  = *(const s16x8*)&Al_lds[ra * 64 + ca];
                bh4[i] = *(const s16x8*)&Bh_lds[rb * 64 + cb];
                bl4[i] = *(const s16x8*)&Bl_lds[rb * 64 + cb];
            }
            #pragma unroll
            for (int i = 0; i < 2; ++i)
                #pragma unroll
                for (int j = 0; j < 2; ++j)
                    acc[i][j] = __builtin_amdgcn_mfma_f32_32x32x16_bf16(ah[i], bh4[j], acc[i][j], 0, 0, 0);
            #pragma unroll
            for (int i = 0; i < 2; ++i)
                #pragma unroll
                for (int j = 0; j < 2; ++j)
                    acc[i][j] = __builtin_amdgcn_mfma_f32_32x32x16_bf16(ah[i], bl4[j], acc[i][j], 0, 0, 0);
            #pragma unroll
            for (int i = 0; i < 2; ++i)
                #pragma unroll
                for (int j = 0; j < 2; ++j)
                    acc[i][j] = __builtin_amdgcn_mfma_f32_32x32x16_bf16(al[i], bh4[j], acc[i][j], 0, 0, 0);
        }
        __syncthreads();
    }

    #pragma unroll
    for (int i = 0; i < 2; ++i) {
        #pragma unroll
        for (int j = 0; j < 2; ++j) {
            int cc = col0 + wc + j * 32 + lr32;
            float bval = bias[cc];
            #pragma unroll
            for (int reg = 0; reg < 16; ++reg) {
                int rr = row0 + wr + i * 32 + (reg & 3) + 8 * (reg >> 2) + 4 * lk2;
                int bb = rr >> 12, l = rr & (LPAD - 1);
                float val = acc[i][j][reg] + bval;
                if (mode == 0) {
                    if (seg < 2) val *= mask[(size_t)bb * LPAD + l] * QKSCALE;
                    size_t oi = (((size_t)bb * NHEADS + (cc >> 6)) * LPAD + l) * DH + (cc & 63);
                    u16 hh2, ll2; split2(val, hh2, ll2);
                    PH[oi] = hh2;
                    PL[oi] = ll2;
                } else {
                    if (l < S_ORIG)
                        outF[((size_t)bb * S_ORIG + l) * HIDDEN + cc] = val;
                }
            }
        }
    }
}

// ---------------------------------------------------------------------------
// Landmarks from Q/K pairs. Emits fp32 QL/KL and QL pairs. grid (128,32), 64t.
// ---------------------------------------------------------------------------
__global__ void k_landmarks(const u16* __restrict__ QPH, const u16* __restrict__ QPL,
                            const u16* __restrict__ KPH, const u16* __restrict__ KPL,
                            float* __restrict__ QL, float* __restrict__ KL,
                            u16* __restrict__ QLPH, u16* __restrict__ QLPL) {
    int n = blockIdx.x, bh = blockIdx.y, d = threadIdx.x;
    size_t base = ((size_t)bh * LPAD + n * 32) * DH + d;
    float sq = 0.f, sk = 0.f;
    #pragma unroll
    for (int s = 0; s < 32; ++s) {
        size_t a = base + (size_t)s * DH;
        sq += bf16f(QPH[a]) + bf16f(QPL[a]);
        sk += bf16f(KPH[a]) + bf16f(KPL[a]);
    }
    float ql = sq * (1.f / 32.f), kl = sk * (1.f / 32.f);
    size_t oi = ((size_t)bh * NLM + n) * DH + d;
    QL[oi] = ql;
    KL[oi] = kl;
    u16 hh2, ll2; split2(ql, hh2, ll2);
    QLPH[oi] = hh2;
    QLPL[oi] = ll2;
}

// ---------------------------------------------------------------------------
// Fused: K2 = softmax(QL @ KL^T)  AND  VA = V0 = K2^T / denom.
// grid (1, 32), 256 threads.
// ---------------------------------------------------------------------------
__global__ __launch_bounds__(256) void k_qlk_v0(const float* __restrict__ QLb,
                                                const float* __restrict__ Bsrc,
                                                float* __restrict__ K2out,
                                                float* __restrict__ VA) {
    __shared__ float Qt[64][132];
    __shared__ float Bt[64][132];
    __shared__ float redx[256];
    int tid = threadIdx.x;
    int tx = tid & 15, ty = tid >> 4;
    int bh = blockIdx.y;
    const float* QLp = QLb + (size_t)bh * NLM * DH;
    const float* Bp = Bsrc + (size_t)bh * NLM * DH;

    #pragma unroll
    for (int q = 0; q < 8; ++q) {
        int idx = tid + q * 256;
        int r = idx >> 4, d4 = idx & 15;
        float4 v = *(const float4*)(QLp + (size_t)r * DH + d4 * 4);
        Qt[d4 * 4 + 0][r] = v.x; Qt[d4 * 4 + 1][r] = v.y;
        Qt[d4 * 4 + 2][r] = v.z; Qt[d4 * 4 + 3][r] = v.w;
        float4 w = *(const float4*)(Bp + (size_t)r * DH + d4 * 4);
        Bt[d4 * 4 + 0][r] = w.x; Bt[d4 * 4 + 1][r] = w.y;
        Bt[d4 * 4 + 2][r] = w.z; Bt[d4 * 4 + 3][r] = w.w;
    }
    __syncthreads();

    float acc[8][8];
    #pragma unroll
    for (int i = 0; i < 8; ++i)
        #pragma unroll
        for (int j = 0; j < 8; ++j) acc[i][j] = 0.f;

    #pragma unroll
    for (int k = 0; k < 64; ++k) {
        float av[8], bv[8];
        float4 t0 = *(const float4*)&Qt[k][ty * 4];
        float4 t1 = *(const float4*)&Qt[k][64 + ty * 4];
        float4 t2 = *(const float4*)&Bt[k][tx * 4];
        float4 t3 = *(const float4*)&Bt[k][64 + tx * 4];
        av[0]=t0.x; av[1]=t0.y; av[2]=t0.z; av[3]=t0.w;
        av[4]=t1.x; av[5]=t1.y; av[6]=t1.z; av[7]=t1.w;
        bv[0]=t2.x; bv[1]=t2.y; bv[2]=t2.z; bv[3]=t2.w;
        bv[4]=t3.x; bv[5]=t3.y; bv[6]=t3.z; bv[7]=t3.w;
        #pragma unroll
        for (int i = 0; i < 8; ++i)
            #pragma unroll
            for (int j = 0; j < 8; ++j)
                acc[i][j] = fmaf(av[i], bv[j], acc[i][j]);
    }

    // softmax (rows private to 16-lane tx groups)
    float m[8], s[8];
    #pragma unroll
    for (int i = 0; i < 8; ++i) {
        m[i] = acc[i][0];
        #pragma unroll
        for (int j = 1; j < 8; ++j) m[i] = fmaxf(m[i], acc[i][j]);
    }
    #pragma unroll
    for (int o = 8; o >= 1; o >>= 1)
        #pragma unroll
        for (int i = 0; i < 8; ++i) m[i] = fmaxf(m[i], __shfl_xor(m[i], o));
    #pragma unroll
    for (int i = 0; i < 8; ++i) {
        s[i] = 0.f;
        #pragma unroll
        for (int j = 0; j < 8; ++j) {
            acc[i][j] = expf(acc[i][j] - m[i]);
            s[i] += acc[i][j];
        }
    }
    #pragma unroll
    for (int o = 8; o >= 1; o >>= 1)
        #pragma unroll
        for (int i = 0; i < 8; ++i) s[i] += __shfl_xor(s[i], o);
    #pragma unroll
    for (int i = 0; i < 8; ++i) {
        float inv = 1.f / s[i];
        #pragma unroll
        for (int j = 0; j < 8; ++j) acc[i][j] *= inv;
    }

    // write K2 (row-major, probs)
    #pragma unroll
    for (int i = 0; i < 8; ++i) {
        int r = (i >> 2) * 64 + ty * 4 + (i & 3);
        #pragma unroll
        for (int jh = 0; jh < 2; ++jh) {
            int c = jh * 64 + tx * 4;
            float4 res;
            res.x = acc[i][jh * 4 + 0]; res.y = acc[i][jh * 4 + 1];
            res.z = acc[i][jh * 4 + 2]; res.w = acc[i][jh * 4 + 3];
            *(float4*)(K2out + ((size_t)bh * NLM + r) * NLM + c) = res;
        }
    }

    // ---- denom: max row-sum (probs >= 0) ----
    float rmax = 0.f;
    #pragma unroll
    for (int i = 0; i < 8; ++i) {
        float rs = 0.f;
        #pragma unroll
        for (int j = 0; j < 8; ++j) rs += acc[i][j];
        rs += __shfl_xor(rs, 1);
        rs += __shfl_xor(rs, 2);
        rs += __shfl_xor(rs, 4);
        rs += __shfl_xor(rs, 8);
        rmax = fmaxf(rmax, rs);
    }
    redx[tid] = rmax;
    __syncthreads();
    for (int st = 128; st > 0; st >>= 1) {
        if (tid < st) redx[tid] = fmaxf(redx[tid], redx[tid + st]);
        __syncthreads();
    }
    float rmax_blk = redx[0];
    __syncthreads();

    // ---- max col-sum (partials via LDS, reuse Qt) ----
    float* colbuf = &Qt[0][0];
    #pragma unroll
    for (int j = 0; j < 8; ++j) {
        int c = (j >> 2) * 64 + tx * 4 + (j & 3);
        float cp = 0.f;
        #pragma unroll
        for (int i = 0; i < 8; ++i) cp += acc[i][j];
        colbuf[ty * 128 + c] = cp;
    }
    __syncthreads();
    float cs = 0.f;
    if (tid < 128) {
        #pragma unroll
        for (int t2 = 0; t2 < 16; ++t2) cs += colbuf[t2 * 128 + tid];
    }
    redx[tid] = cs;
    __syncthreads();
    for (int st = 128; st > 0; st >>= 1) {
        if (tid < st) redx[tid] = fmaxf(redx[tid], redx[tid + st]);
        __syncthreads();
    }
    float invden = 1.f / (rmax_blk * redx[0]);

    // ---- VA = K2^T * invden (transposed scalar writes) ----
    float* VAp = VA + (size_t)bh * NLM * NLM;
    #pragma unroll
    for (int i = 0; i < 8; ++i) {
        int r = (i >> 2) * 64 + ty * 4 + (i & 3);
        #pragma unroll
        for (int j = 0; j < 8; ++j) {
            int c = (j >> 2) * 64 + tx * 4 + (j & 3);
            VAp[(size_t)c * NLM + r] = acc[i][j] * invden;
        }
    }
}

// ---------------------------------------------------------------------------
// Batched matmul: C = alpha*(A@B) + sI  (A 128x128, B 128xN). fp32 VALU.
// 32x32 tiles, grid (N/32, 4, 32) -> fills all CUs per step.
// ---------------------------------------------------------------------------
__global__ __launch_bounds__(256) void k_bmm(const float* __restrict__ Ab,
                                             const float* __restrict__ Bb,
                                             float* __restrict__ Cb,
                                             float* __restrict__ C2b,
                                             int N, float alpha, float sI,
                                             float alpha2, float sI2) {
    __shared__ float At[128][36];
    __shared__ float Bs[128][36];
    int tid = threadIdx.x;
    int tx = tid & 15, ty = tid >> 4;
    int bh = blockIdx.z;
    int r0 = blockIdx.y * 32, c0 = blockIdx.x * 32;
    const float* A = Ab + (size_t)bh * NLM * NLM;
    const float* Bm = Bb + (size_t)bh * NLM * N;

    #pragma unroll
    for (int q = 0; q < 4; ++q) {
        int idx = tid + q * 256;
        int r = idx >> 5, k4 = idx & 31;
        float4 v = *(const float4*)(A + (size_t)(r0 + r) * NLM + k4 * 4);
        At[k4 * 4 + 0][r] = v.x; At[k4 * 4 + 1][r] = v.y;
        At[k4 * 4 + 2][r] = v.z; At[k4 * 4 + 3][r] = v.w;
        int bk = idx >> 3, c4 = idx & 7;
        float4 w = *(const float4*)(Bm + (size_t)bk * N + c0 + c4 * 4);
        *(float4*)&Bs[bk][c4 * 4] = w;
    }
    __syncthreads();

    float acc[2][2] = {};
    #pragma unroll 8
    for (int k = 0; k < 128; ++k) {
        float2 a2 = *(const float2*)&At[k][ty * 2];
        float2 b2 = *(const float2*)&Bs[k][tx * 2];
        acc[0][0] = fmaf(a2.x, b2.x, acc[0][0]);
        acc[0][1] = fmaf(a2.x, b2.y, acc[0][1]);
        acc[1][0] = fmaf(a2.y, b2.x, acc[1][0]);
        acc[1][1] = fmaf(a2.y, b2.y, acc[1][1]);
    }

    float* C = Cb + (size_t)bh * NLM * N;
    float* C2 = C2b ? (C2b + (size_t)bh * NLM * N) : nullptr;
    #pragma unroll
    for (int i = 0; i < 2; ++i) {
        int gr = r0 + ty * 2 + i;
        #pragma unroll
        for (int j = 0; j < 2; ++j) {
            int gc = c0 + tx * 2 + j;
            float idadd = (gr == gc) ? 1.f : 0.f;
            C[(size_t)gr * N + gc] = alpha * acc[i][j] + sI * idadd;
            if (C2) C2[(size_t)gr * N + gc] = alpha2 * acc[i][j] + sI2 * idadd;
        }
    }
}

// ---------------------------------------------------------------------------
// Flash-style fused kernel_3 path, pair inputs. Grid (8 sp, 2 qh, 32 bh).
// KV-tile = 64, LDS 64 KB (2 WG/CU).
// ---------------------------------------------------------------------------
__global__ __launch_bounds__(256) void k_flashk3(const u16* __restrict__ QLPH,
                                                 const u16* __restrict__ QLPL,
                                                 const u16* __restrict__ KPH,
                                                 const u16* __restrict__ KPL,
                                                 const u16* __restrict__ VPH,
                                                 const u16* __restrict__ VPL,
                                                 const float* __restrict__ mask,
                                                 float* __restrict__ PO,
                                                 float* __restrict__ ML) {
    __shared__ u16 lds[32768];        // 64 KB
    u16* QLh = lds;                   // 64x64 each plane (4096 u16)
    u16* QLl = lds + 4096;
    u16* Kh  = lds + 8192;            // 64x64
    u16* Kl  = lds + 12288;
    u16* Vth = lds + 16384;           // 64x64 (V transposed [d][n])
    u16* Vtl = lds + 20480;
    u16* Ph  = lds + 24576;           // 64x64
    u16* Pl  = lds + 28672;

    int tid = threadIdx.x;
    int lane = tid & 63, wv = tid >> 6;
    int lr = lane & 15, lk = lane >> 4;
    int sp = blockIdx.x, qh = blockIdx.y, bh = blockIdx.z;
    int b = bh >> 4;
    int q0 = qh * 64;
    int wr16 = wv * 16;               // wave's 16 rows (local 0..63)

    // ---- stage QL pairs via global_load_lds (inverse-swizzled source) ----
    #pragma unroll
    for (int q = 0; q < 2; ++q) {
        int idx = tid + q * 256;
        int r = idx >> 3, sc = idx & 7;
        int csrc = (sc ^ (r & 7)) * 8;
        size_t g = ((size_t)bh * NLM + q0 + r) * DH + csrc;
        __builtin_amdgcn_global_load_lds(
            (const __attribute__((address_space(1))) void*)(QLPH + g),
            (__attribute__((address_space(3))) void*)(&QLh[idx * 8]), 16, 0, 0);
        __builtin_amdgcn_global_load_lds(
            (const __attribute__((address_space(1))) void*)(QLPL + g),
            (__attribute__((address_space(3))) void*)(&QLl[idx * 8]), 16, 0, 0);
    }

    float m_run[4] = {-1e30f, -1e30f, -1e30f, -1e30f};
    float l_run[4] = {0.f, 0.f, 0.f, 0.f};
    f32x4 t5[4] = {};                 // rows wr16+lk*4+q, cols d=j*16+lr

    for (int t = 0; t < 8; ++t) {
        int kt0 = sp * 512 + t * 64;
        // ---- stage K pairs via global_load_lds (64 rows) ----
        #pragma unroll
        for (int q = 0; q < 2; ++q) {
            int idx = tid + q * 256;
            int r = idx >> 3, sc = idx & 7;
            int csrc = (sc ^ (r & 7)) * 8;
            size_t g = ((size_t)bh * LPAD + kt0 + r) * DH + csrc;
            __builtin_amdgcn_global_load_lds(
                (const __attribute__((address_space(1))) void*)(KPH + g),
                (__attribute__((address_space(3))) void*)(&Kh[idx * 8]), 16, 0, 0);
            __builtin_amdgcn_global_load_lds(
                (const __attribute__((address_space(1))) void*)(KPL + g),
                (__attribute__((address_space(3))) void*)(&Kl[idx * 8]), 16, 0, 0);
        }
        // ---- stage V transposed (pairs; row-fixed contiguous writes) ----
        #pragma unroll
        for (int q = 0; q < 4; ++q) {
            int idx = tid + q * 256;
            int n = idx & 63, dg = idx >> 6;      // dg 0..15
            int d4 = dg * 4;
            size_t g = ((size_t)bh * LPAD + kt0 + n) * DH + d4;
            ushort4 h4 = *(const ushort4*)(VPH + g);
            ushort4 l4 = *(const ushort4*)(VPL + g);
            #pragma unroll
            for (int e = 0; e < 4; ++e) {
                Vth[IDX64(d4 + e, n)] = (&h4.x)[e];
                Vtl[IDX64(d4 + e, n)] = (&l4.x)[e];
            }
        }
        __syncthreads();

        // ---- S = QL @ K^T : wave 16 rows x 64 cols (t4[4]) ----
        f32x4 t4[4] = {};
        #pragma unroll
        for (int tt = 0; tt < 3; ++tt) {
            const u16* Xs = (tt == 2) ? QLl : QLh;
            const u16* Ys = (tt == 1) ? Kl : Kh;
            #pragma unroll
            for (int kc = 0; kc < 2; ++kc) {
                s16x8 a = *(const s16x8*)&Xs[IDX64(wr16 + lr, kc * 32 + lk * 8)];
                s16x8 bfr[4];
                #pragma unroll
                for (int j = 0; j < 4; ++j)
                    bfr[j] = *(const s16x8*)&Ys[IDX64(j * 16 + lr, kc * 32 + lk * 8)];
                #pragma unroll
                for (int j = 0; j < 4; ++j)
                    t4[j] = __builtin_amdgcn_mfma_f32_16x16x32_bf16(a, bfr[j], t4[j], 0, 0, 0);
            }
        }

        // ---- mask penalty ----
        #pragma unroll
        for (int j = 0; j < 4; ++j) {
            float pen = 1e9f * (1.f - mask[(size_t)b * LPAD + kt0 + j * 16 + lr]);
            #pragma unroll
            for (int q = 0; q < 4; ++q) t4[j][q] -= pen;
        }

        // ---- online softmax per row (16-lane group reduce over 64 cols) ----
        float alpha[4];
        #pragma unroll
        for (int q = 0; q < 4; ++q) {
            float tm = t4[0][q];
            #pragma unroll
            for (int j = 1; j < 4; ++j) tm = fmaxf(tm, t4[j][q]);
            tm = fmaxf(tm, __shfl_xor(tm, 1));
            tm = fmaxf(tm, __shfl_xor(tm, 2));
            tm = fmaxf(tm, __shfl_xor(tm, 4));
            tm = fmaxf(tm, __shfl_xor(tm, 8));
            float mn = fmaxf(m_run[q], tm);
            float al = expf(m_run[q] - mn);
            float s = 0.f;
            #pragma unroll
            for (int j = 0; j < 4; ++j) {
                t4[j][q] = expf(t4[j][q] - mn);
                s += t4[j][q];
            }
            s += __shfl_xor(s, 1);
            s += __shfl_xor(s, 2);
            s += __shfl_xor(s, 4);
            s += __shfl_xor(s, 8);
            l_run[q] = l_run[q] * al + s;
            m_run[q] = mn;
            alpha[q] = al;
        }
        // rescale O accumulator
        #pragma unroll
        for (int j = 0; j < 4; ++j)
            #pragma unroll
            for (int q = 0; q < 4; ++q) t5[j][q] *= alpha[q];

        // ---- write P pair (wave-private rows; no barrier needed before PV) ----
        #pragma unroll
        for (int j = 0; j < 4; ++j) {
            int col = j * 16 + lr;
            #pragma unroll
            for (int q = 0; q < 4; ++q) {
                int row = wr16 + lk * 4 + q;
                u16 hh2, ll2; split2(t4[j][q], hh2, ll2);
                Ph[IDX64(row, col)] = hh2;
                Pl[IDX64(row, col)] = ll2;
            }
        }

        // ---- O += P @ V (K=64, 3 split terms): wave 16 rows x 64 cols ----
        #pragma unroll
        for (int tt = 0; tt < 3; ++tt) {
            const u16* Xs = (tt == 2) ? Pl : Ph;
            const u16* Ys = (tt == 1) ? Vtl : Vth;
            #pragma unroll
            for (int kc = 0; kc < 2; ++kc) {
                s16x8 a = *(const s16x8*)&Xs[IDX64(wr16 + lr, kc * 32 + lk * 8)];
                s16x8 bfr[4];
                #pragma unroll
                for (int j = 0; j < 4; ++j)
                    bfr[j] = *(const s16x8*)&Ys[IDX64(j * 16 + lr, kc * 32 + lk * 8)];
                #pragma unroll
                for (int j = 0; j < 4; ++j)
                    t5[j] = __builtin_amdgcn_mfma_f32_16x16x32_bf16(a, bfr[j], t5[j], 0, 0, 0);
            }
        }
        __syncthreads();   // protect K/V/P before next tile's staging
    }

    // ---- emit partials ----
    size_t pb = (size_t)(bh * 16 + qh * 8 + sp) * 64;
    #pragma unroll
    for (int j = 0; j < 4; ++j) {
        int d = j * 16 + lr;
        #pragma unroll
        for (int q = 0; q < 4; ++q) {
            int row = wr16 + lk * 4 + q;
            PO[(pb + row) * 64 + d] = t5[j][q];
        }
    }
    if (lr == 0) {
        #pragma unroll
        for (int q = 0; q < 4; ++q) {
            int row = wr16 + lk * 4 + q;
            ML[(pb + row) * 2 + 0] = m_run[q];
            ML[(pb + row) * 2 + 1] = l_run[q];
        }
    }
}

// Combine 8 split-K partials -> K3V[bh][128][64].
__global__ void k_flash_combine(const float* __restrict__ PO,
                                const float* __restrict__ ML,
                                float* __restrict__ K3V) {
    int idx = blockIdx.x * 256 + threadIdx.x;
    int bh = idx >> 13, rem = idx & 8191;
    int g = rem >> 6, d = rem & 63;
    int qh = g >> 6, rl = g & 63;
    size_t rb = (size_t)(bh * 16 + qh * 8) * 64 + rl;
    float mstar = -1e30f;
    #pragma unroll
    for (int sp = 0; sp < 8; ++sp)
        mstar = fmaxf(mstar, ML[(rb + (size_t)sp * 64) * 2]);
    float osum = 0.f, lsum = 0.f;
    #pragma unroll
    for (int sp = 0; sp < 8; ++sp) {
        size_t r = rb + (size_t)sp * 64;
        float wgt = expf(ML[r * 2] - mstar);
        osum += wgt * PO[r * 64 + d];
        lsum += wgt * ML[r * 2 + 1];
    }
    K3V[idx] = osum / lsum;
}

// ---------------------------------------------------------------------------
// kernel_1 fused via split-bf16 MFMA: ATTN = softmax(Q_tile @ KL^T) @ MM.
// Q staged from pairs via global_load_lds (async, no VALU split).
// ---------------------------------------------------------------------------
__global__ __launch_bounds__(256) void k_attn(const u16* __restrict__ QPH,
                                              const u16* __restrict__ QPL,
                                              const float* __restrict__ KLb,
                                              const float* __restrict__ MMb,
                                              u16* __restrict__ ATH,
                                              u16* __restrict__ ATL) {
    __shared__ u16 lds[49152];
    u16* Qh  = lds;               // 8192 (128x64)
    u16* Ql  = lds + 8192;
    u16* KLh = lds + 16384;
    u16* KLl = lds + 24576;
    u16* Ph  = lds;               // 16384 (128x128), overwrites Q/KL
    u16* Pl  = lds + 16384;
    u16* Mth = lds + 32768;       // 8192 (64x128)
    u16* Mtl = lds + 40960;

    int tid = threadIdx.x;
    int lane = tid & 63, wv = tid >> 6;
    int lr = lane & 15, lk = lane >> 4;
    int l0 = blockIdx.x * 128, bh = blockIdx.y;
    int b = bh >> 4, hh = bh & 15;
    int wrA = wv * 32;            // wave's 32 rows (both matmuls)

    // ---- stage Q pairs via global_load_lds (inverse-swizzled source) ----
    #pragma unroll
    for (int q = 0; q < 4; ++q) {
        int idx = tid + q * 256;
        int r = idx >> 3, sc = idx & 7;
        int csrc = (sc ^ (r & 7)) * 8;
        size_t g = ((size_t)bh * LPAD + l0 + r) * DH + csrc;
        __builtin_amdgcn_global_load_lds(
            (const __attribute__((address_space(1))) void*)(QPH + g),
            (__attribute__((address_space(3))) void*)(&Qh[idx * 8]), 16, 0, 0);
        __builtin_amdgcn_global_load_lds(
            (const __attribute__((address_space(1))) void*)(QPL + g),
            (__attribute__((address_space(3))) void*)(&Ql[idx * 8]), 16, 0, 0);
    }
    // ---- stage KL (fp32 -> split, IDX64) ----
    #pragma unroll
    for (int q = 0; q < 4; ++q) {
        int idx = tid + q * 256;
        int r = idx >> 3, c8 = (idx & 7) * 8;
        float4 w0 = *(const float4*)(KLb + ((size_t)bh * NLM + r) * DH + c8);
        float4 w1 = *(const float4*)(KLb + ((size_t)bh * NLM + r) * DH + c8 + 4);
        float ys[8] = {w0.x, w0.y, w0.z, w0.w, w1.x, w1.y, w1.z, w1.w};
        s16x8 h8, l8;
        #pragma unroll
        for (int e = 0; e < 8; ++e) {
            u16 hh2, ll2; split2(ys[e], hh2, ll2);
            h8[e] = (short)hh2; l8[e] = (short)ll2;
        }
        *(s16x8*)&KLh[IDX64(r, c8)] = h8;
        *(s16x8*)&KLl[IDX64(r, c8)] = l8;
    }
    // ---- stage MM transposed (split, IDX128) ----
    #pragma unroll
    for (int q = 0; q < 8; ++q) {
        int idx = tid + q * 256;
        int n = idx >> 4, d4 = (idx & 15) * 4;
        float4 v = *(const float4*)(MMb + ((size_t)bh * NLM + n) * DH + d4);
        float xs[4] = {v.x, v.y, v.z, v.w};
        #pragma unroll
        for (int e = 0; e < 4; ++e) {
            u16 hh2, ll2; split2(xs[e], hh2, ll2);
            Mth[IDX128(d4 + e, n)] = hh2;
            Mtl[IDX128(d4 + e, n)] = ll2;
        }
    }
    __syncthreads();

    // ---- S = Q @ KL^T : wave owns 32 rows x 128 cols (t4[2][8]) ----
    f32x4 t4[2][8] = {};
    #pragma unroll
    for (int t = 0; t < 3; ++t) {
        const u16* Xs = (t == 2) ? Ql : Qh;
        const u16* Ys = (t == 1) ? KLl : KLh;
        #pragma unroll
        for (int kc = 0; kc < 2; ++kc) {
            s16x8 a[2], bfr[8];
            #pragma unroll
            for (int i = 0; i < 2; ++i)
                a[i] = *(const s16x8*)&Xs[IDX64(wrA + i * 16 + lr, kc * 32 + lk * 8)];
            #pragma unroll
            for (int j = 0; j < 8; ++j)
                bfr[j] = *(const s16x8*)&Ys[IDX64(j * 16 + lr, kc * 32 + lk * 8)];
            #pragma unroll
            for (int i = 0; i < 2; ++i)
                #pragma unroll
                for (int j = 0; j < 8; ++j)
                    t4[i][j] = __builtin_amdgcn_mfma_f32_16x16x32_bf16(a[i], bfr[j], t4[i][j], 0, 0, 0);
        }
    }

    // ---- row softmax ----
    #pragma unroll
    for (int i = 0; i < 2; ++i)
        #pragma unroll
        for (int q = 0; q < 4; ++q) {
            float m = t4[i][0][q];
            #pragma unroll
            for (int j = 1; j < 8; ++j) m = fmaxf(m, t4[i][j][q]);
            m = fmaxf(m, __shfl_xor(m, 1));
            m = fmaxf(m, __shfl_xor(m, 2));
            m = fmaxf(m, __shfl_xor(m, 4));
            m = fmaxf(m, __shfl_xor(m, 8));
            float s = 0.f;
            #pragma unroll
            for (int j = 0; j < 8; ++j) {
                t4[i][j][q] = expf(t4[i][j][q] - m);
                s += t4[i][j][q];
            }
            s += __shfl_xor(s, 1);
            s += __shfl_xor(s, 2);
            s += __shfl_xor(s, 4);
            s += __shfl_xor(s, 8);
            float inv = 1.f / s;
            #pragma unroll
            for (int j = 0; j < 8; ++j) t4[i][j][q] *= inv;
        }

    __syncthreads();   // Q/KL reads done; safe to overwrite with P
    #pragma unroll
    for (int i = 0; i < 2; ++i)
        #pragma unroll
        for (int j = 0; j < 8; ++j) {
            int col = j * 16 + lr;
            #pragma unroll
            for (int q = 0; q < 4; ++q) {
                int row = wrA + i * 16 + lk * 4 + q;
                u16 hh2, ll2; split2(t4[i][j][q], hh2, ll2);
                Ph[IDX128(row, col)] = hh2;
                Pl[IDX128(row, col)] = ll2;
            }
        }
    __syncthreads();

    // ---- O = P @ MM (K=128, 3 split terms) ----
    f32x4 t5[2][4] = {};
    #pragma unroll
    for (int t = 0; t < 3; ++t) {
        const u16* Xs = (t == 2) ? Pl : Ph;
        const u16* Ys = (t == 1) ? Mtl : Mth;
        #pragma unroll
        for (int kc = 0; kc < 4; ++kc) {
            s16x8 a[2], bfr[4];
            #pragma unroll
            for (int i = 0; i < 2; ++i)
                a[i] = *(const s16x8*)&Xs[IDX128(wrA + i * 16 + lr, kc * 32 + lk * 8)];
            #pragma unroll
            for (int j = 0; j < 4; ++j)
                bfr[j] = *(const s16x8*)&Ys[IDX128(j * 16 + lr, kc * 32 + lk * 8)];
            #pragma unroll
            for (int i = 0; i < 2; ++i)
                #pragma unroll
                for (int j = 0; j < 4; ++j)
                    t5[i][j] = __builtin_amdgcn_mfma_f32_16x16x32_bf16(a[i], bfr[j], t5[i][j], 0, 0, 0);
        }
    }

    // ---- epilogue: split O -> ATH/ATL ----
    #pragma unroll
    for (int i = 0; i < 2; ++i)
        #pragma unroll
        for (int j = 0; j < 4; ++j) {
            int d = j * 16 + lr;
            #pragma unroll
            for (int q = 0; q < 4; ++q) {
                int l = l0 + wrA + i * 16 + lk * 4 + q;
                size_t base = ((size_t)b * LPAD + l) * HIDDEN + hh * DH + d;
                u16 hh2, ll2; split2(t5[i][j][q], hh2, ll2);
                ATH[base] = hh2;
                ATL[base] = ll2;
            }
        }
}

// ---------------------------------------------------------------------------
extern "C" void kernel_launch(void* const* d_in, const int* in_sizes, int n_in,
                              void* d_out, int out_size, void* d_ws, size_t ws_size,
                              hipStream_t stream) {
    (void)in_sizes; (void)n_in; (void)out_size; (void)ws_size;
    const float* X    = (const float*)d_in[0];
    const float* mask = (const float*)d_in[1];
    const float* Wq   = (const float*)d_in[2];
    const float* bq   = (const float*)d_in[3];
    const float* Wk   = (const float*)d_in[4];
    const float* bk   = (const float*)d_in[5];
    const float* Wv   = (const float*)d_in[6];
    const float* bv   = (const float*)d_in[7];
    const float* Wo   = (const float*)d_in[8];
    const float* bo   = (const float*)d_in[9];
    float* out = (float*)d_out;
    float* w = (float*)d_ws;

    size_t o = 0;
    u16* WQH = (u16*)(w + o); o += (size_t)HIDDEN * HIDDEN / 2;
    u16* WQL = (u16*)(w + o); o += (size_t)HIDDEN * HIDDEN / 2;
    u16* WKH = (u16*)(w + o); o += (size_t)HIDDEN * HIDDEN / 2;
    u16* WKL = (u16*)(w + o); o += (size_t)HIDDEN * HIDDEN / 2;
    u16* WVH = (u16*)(w + o); o += (size_t)HIDDEN * HIDDEN / 2;
    u16* WVL = (u16*)(w + o); o += (size_t)HIDDEN * HIDDEN / 2;
    u16* WOH = (u16*)(w + o); o += (size_t)HIDDEN * HIDDEN / 2;
    u16* WOL = (u16*)(w + o); o += (size_t)HIDDEN * HIDDEN / 2;
    float* Q   = w + o; o += (size_t)BHT * LPAD * DH;   // Q pairs
    float* K   = w + o; o += (size_t)BHT * LPAD * DH;   // K pairs
    float* V   = w + o; o += (size_t)BHT * LPAD * DH;   // V pairs
    float* QL  = w + o; o += (size_t)BHT * NLM * DH;
    float* KL  = w + o; o += (size_t)BHT * NLM * DH;
    float* K2  = w + o; o += (size_t)BHT * NLM * NLM;
    float* VA  = w + o; o += (size_t)BHT * NLM * NLM;
    float* VB  = w + o; o += (size_t)BHT * NLM * NLM;
    float* KV  = w + o; o += (size_t)BHT * NLM * NLM;
    float* P1  = w + o; o += (size_t)BHT * NLM * NLM;
    float* T3  = w + o; o += (size_t)BHT * NLM * NLM;
    float* PK  = w + o; o += (size_t)BHT * 16 * NLM * DH;
    float* K3V = w + o; o += (size_t)BHT * NLM * DH;
    float* MM  = w + o; o += (size_t)BHT * NLM * DH;
    float* SC  = w + o; o += (size_t)BHT * NLM * LPAD;

    // Q/K/V buffers hold bf16 pairs (exact fit: fp32 size == 2 u16 planes)
    u16* QPH = (u16*)Q;
    u16* QPL = QPH + (size_t)BHT * LPAD * DH;
    u16* KPH = (u16*)K;
    u16* KPL = KPH + (size_t)BHT * LPAD * DH;
    u16* VPH = (u16*)V;
    u16* VPL = VPH + (size_t)BHT * LPAD * DH;

    // Flash partials live in PK (PO 8.4 MB + ML 0.26 MB < 16.8 MB).
    float* PO = PK;
    float* ML = PK + (size_t)BHT * 16 * 64 * 64;

    // Time-shared aliases of the SC region (disjoint live windows):
    u16* XH  = (u16*)SC;
    u16* XL  = XH + (size_t)2 * LPAD * HIDDEN;
    u16* ATH = (u16*)SC;
    u16* ATL = ATH + (size_t)2 * LPAD * HIDDEN;
    // QL pairs: placed far past XH/XL and ATH/ATL regions within SC.
    u16* QLPH = (u16*)SC + (size_t)32 * 1024 * 1024;
    u16* QLPL = QLPH + (size_t)BHT * NLM * DH;

    k_split_x<<<8192, 256, 0, stream>>>(X, XH, XL);
    k_split_w4<<<dim3(1024, 4), 256, 0, stream>>>(Wq, Wk, Wv, Wo,
        WQH, WQL, WKH, WKL, WVH, WVL, WOH, WOL);

    // Fused QKV projection: one launch, grid (64, 24). All outputs pairs.
    k_gemm_bf16<<<dim3(64, 24), 256, 0, stream>>>(
        XH, XL, WQH, WQL, WKH, WKL, WVH, WVL, bq, bk, bv, mask,
        QPH, QPL, KPH, KPL, VPH, VPL, nullptr, 0);

    k_landmarks<<<dim3(NLM, BHT), 64, 0, stream>>>(QPH, QPL, KPH, KPL, QL, KL, QLPH, QLPL);

    // K2 softmax + V0/denom fused
    k_qlk_v0<<<dim3(1, BHT), 256, 0, stream>>>(QL, KL, K2, VA);

    k_flashk3<<<dim3(8, 2, BHT), 256, 0, stream>>>(QLPH, QLPL, KPH, KPL, VPH, VPL, mask, PO, ML);
    k_flash_combine<<<(BHT * NLM * DH) / 256, 256, 0, stream>>>(PO, ML, K3V);

    float* cur = VA;
    float* nxt = VB;
    for (int it = 0; it < 6; ++it) {
        k_bmm<<<dim3(4, 4, BHT), 256, 0, stream>>>(K2, cur, KV, P1, NLM, 1.f, 0.f, -1.f, 7.f);
        k_bmm<<<dim3(4, 4, BHT), 256, 0, stream>>>(KV, P1, T3, nullptr, NLM, -1.f, 15.f, 0.f, 0.f);
        k_bmm<<<dim3(4, 4, BHT), 256, 0, stream>>>(KV, T3, P1, nullptr, NLM, -1.f, 13.f, 0.f, 0.f);
        k_bmm<<<dim3(4, 4, BHT), 256, 0, stream>>>(cur, P1, nxt, nullptr, NLM, 0.25f, 0.f, 0.f, 0.f);
        float* t = cur; cur = nxt; nxt = t;
    }

    k_bmm<<<dim3(2, 4, BHT), 256, 0, stream>>>(cur, K3V, MM, nullptr, DH, 1.f, 0.f, 0.f, 0.f);

    k_attn<<<dim3(32, BHT), 256, 0, stream>>>(QPH, QPL, KL, MM, ATH, ATL);

    // Final projection: grid (64, 8), mode 1 (B0 slot = Wo).
    k_gemm_bf16<<<dim3(64, 8), 256, 0, stream>>>(
        ATH, ATL, WOH, WOL, nullptr, nullptr, nullptr, nullptr, bo, nullptr,
        nullptr, nullptr, nullptr, nullptr, nullptr, nullptr, nullptr, nullptr, out, 1);
}

// Round 20
// 540.707 us; speedup vs baseline: 1.0489x; 1.0489x over previous
//
#include <hip/hip_runtime.h>
#include <hip/hip_bf16.h>
#include <math.h>

#define S_ORIG 4095
#define LPAD   4096
#define NHEADS 16
#define DH     64
#define NLM    128
#define BHT    32        // B * NHEADS
#define HIDDEN 1024
#define QKSCALE 0.35355339059327373f   // 1 / 64^0.25

typedef unsigned short u16;
typedef short s16x8 __attribute__((ext_vector_type(8)));
typedef float f32x4 __attribute__((ext_vector_type(4)));

// XOR-swizzled LDS indices (spread row-stride power-of-2 across banks)
#define IDX64(r, c)  ((r) * 64 + ((c) ^ (((r) & 7) << 3)))
#define IDX128(r, c) ((r) * 128 + ((c) ^ (((r) & 7) << 3)))

// ---------------------------------------------------------------------------
__device__ inline void split2(float x, u16& h, u16& l) {
    __hip_bfloat16 bh = __float2bfloat16(x);
    float fh = __bfloat162float(bh);
    __hip_bfloat16 bl = __float2bfloat16(x - fh);
    h = *(u16*)&bh;
    l = *(u16*)&bl;
}

__device__ inline float bf16f(u16 b) {
    unsigned u = ((unsigned)b) << 16;
    return *(float*)&u;
}

// X (B,4095,1024) fp32 -> XH, XL (8192,1024) bf16-bits, pad row (l==4095) zero.
__global__ __launch_bounds__(256) void k_split_x(const float* __restrict__ X,
                                                 u16* __restrict__ XH,
                                                 u16* __restrict__ XL) {
    int idx = blockIdx.x * 256 + threadIdx.x;      // one thread = 4 elems
    int gr = idx >> 8;                             // row 0..8191
    int c4 = (idx & 255) * 4;
    int b = gr >> 12, l = gr & (LPAD - 1);
    float4 v = make_float4(0.f, 0.f, 0.f, 0.f);
    if (l < S_ORIG) v = *(const float4*)(X + ((size_t)b * S_ORIG + l) * HIDDEN + c4);
    ushort4 h4, l4;
    split2(v.x, h4.x, l4.x); split2(v.y, h4.y, l4.y);
    split2(v.z, h4.z, l4.z); split2(v.w, h4.w, l4.w);
    size_t o = (size_t)gr * HIDDEN + c4;
    *(ushort4*)(XH + o) = h4;
    *(ushort4*)(XL + o) = l4;
}

// All four weights split in one launch. grid (1024, 4).
__global__ __launch_bounds__(256) void k_split_w4(
    const float* __restrict__ W0, const float* __restrict__ W1,
    const float* __restrict__ W2, const float* __restrict__ W3,
    u16* __restrict__ H0, u16* __restrict__ L0,
    u16* __restrict__ H1, u16* __restrict__ L1,
    u16* __restrict__ H2, u16* __restrict__ L2,
    u16* __restrict__ H3, u16* __restrict__ L3) {
    int ws = blockIdx.y;
    const float* W = (ws == 0) ? W0 : (ws == 1) ? W1 : (ws == 2) ? W2 : W3;
    u16* H = (ws == 0) ? H0 : (ws == 1) ? H1 : (ws == 2) ? H2 : H3;
    u16* L = (ws == 0) ? L0 : (ws == 1) ? L1 : (ws == 2) ? L2 : L3;
    int idx = blockIdx.x * 256 + threadIdx.x;
    size_t o = (size_t)idx * 4;
    float4 v = *(const float4*)(W + o);
    ushort4 h4, l4;
    split2(v.x, h4.x, l4.x); split2(v.y, h4.y, l4.y);
    split2(v.z, h4.z, l4.z); split2(v.w, h4.w, l4.w);
    *(ushort4*)(H + o) = h4;
    *(ushort4*)(L + o) = l4;
}

// ---------------------------------------------------------------------------
// Split-bf16 MFMA GEMM, BK=64 (96 MFMA per barrier pair), 64 KB LDS.
// mode 0: fused QKV, all outputs as bf16 PAIRS (Q/K/V). blockIdx.y:
//         seg = y>>3 (0=Q+mask, 1=K+mask, 2=V), col0 = (y&7)*128.
// mode 1: final projection (B0 slot), fp32 out rows l < 4095, grid y = 8.
// ---------------------------------------------------------------------------
__global__ __launch_bounds__(256) void k_gemm_bf16(
    const u16* __restrict__ AH, const u16* __restrict__ AL,
    const u16* __restrict__ B0H, const u16* __restrict__ B0L,
    const u16* __restrict__ B1H, const u16* __restrict__ B1L,
    const u16* __restrict__ B2H, const u16* __restrict__ B2L,
    const float* __restrict__ bias0, const float* __restrict__ bias1,
    const float* __restrict__ bias2, const float* __restrict__ mask,
    u16* __restrict__ QPH, u16* __restrict__ QPL,
    u16* __restrict__ KPH, u16* __restrict__ KPL,
    u16* __restrict__ VPH, u16* __restrict__ VPL,
    float* __restrict__ outF, int mode)
{
    __shared__ u16 Ah_lds[128 * 64];
    __shared__ u16 Al_lds[128 * 64];
    __shared__ u16 Bh_lds[128 * 64];
    __shared__ u16 Bl_lds[128 * 64];
    int tid = threadIdx.x;
    int seg = (mode == 0) ? (blockIdx.y >> 3) : 0;
    int row0 = blockIdx.x * 128;
    int col0 = (mode == 0) ? ((blockIdx.y & 7) * 128) : (blockIdx.y * 128);
    const u16* BH = (seg == 0) ? B0H : (seg == 1) ? B1H : B2H;
    const u16* BL = (seg == 0) ? B0L : (seg == 1) ? B1L : B2L;
    const float* bias = (seg == 0) ? bias0 : (seg == 1) ? bias1 : bias2;
    u16* PH = (seg == 0) ? QPH : (seg == 1) ? KPH : VPH;
    u16* PL = (seg == 0) ? QPL : (seg == 1) ? KPL : VPL;

    int lane = tid & 63, wv = tid >> 6;
    int wr = (wv >> 1) * 64, wc = (wv & 1) * 64;
    int lr = lane & 15, lk = lane >> 4;
    int sr8 = tid >> 3, sc = tid & 7;              // staging row base, chunk 0..7

    f32x4 acc[4][4] = {};

    for (int kt = 0; kt < 1024; kt += 64) {
        #pragma unroll
        for (int h = 0; h < 4; ++h) {
            int r = sr8 + h * 32;
            int csrc = (sc ^ (r & 7)) * 8;         // inverse-swizzled source col
            size_t ga = (size_t)(row0 + r) * HIDDEN + kt + csrc;
            size_t gb = (size_t)(col0 + r) * HIDDEN + kt + csrc;
            int ldst = r * 64 + sc * 8;            // linear dest (lane*16B)
            __builtin_amdgcn_global_load_lds(
                (const __attribute__((address_space(1))) void*)(AH + ga),
                (__attribute__((address_space(3))) void*)(&Ah_lds[ldst]), 16, 0, 0);
            __builtin_amdgcn_global_load_lds(
                (const __attribute__((address_space(1))) void*)(AL + ga),
                (__attribute__((address_space(3))) void*)(&Al_lds[ldst]), 16, 0, 0);
            __builtin_amdgcn_global_load_lds(
                (const __attribute__((address_space(1))) void*)(BH + gb),
                (__attribute__((address_space(3))) void*)(&Bh_lds[ldst]), 16, 0, 0);
            __builtin_amdgcn_global_load_lds(
                (const __attribute__((address_space(1))) void*)(BL + gb),
                (__attribute__((address_space(3))) void*)(&Bl_lds[ldst]), 16, 0, 0);
        }
        __syncthreads();
        #pragma unroll
        for (int kc = 0; kc < 2; ++kc) {
            s16x8 ah[4], al[4], bh4[4], bl4[4];
            #pragma unroll
            for (int i = 0; i < 4; ++i) {
                int ra = wr + i * 16 + lr;
                int rb = wc + i * 16 + lr;
                int ca = (((kc << 2) + lk) ^ (ra & 7)) * 8;   // swizzled read col
                int cb = (((kc << 2) + lk) ^ (rb & 7)) * 8;
                ah[i]  = *(const s16x8*)&Ah_lds[ra * 64 + ca];
                al[i]  = *(const s16x8*)&Al_lds[ra * 64 + ca];
                bh4[i] = *(const s16x8*)&Bh_lds[rb * 64 + cb];
                bl4[i] = *(const s16x8*)&Bl_lds[rb * 64 + cb];
            }
            #pragma unroll
            for (int i = 0; i < 4; ++i)
                #pragma unroll
                for (int j = 0; j < 4; ++j)
                    acc[i][j] = __builtin_amdgcn_mfma_f32_16x16x32_bf16(ah[i], bh4[j], acc[i][j], 0, 0, 0);
            #pragma unroll
            for (int i = 0; i < 4; ++i)
                #pragma unroll
                for (int j = 0; j < 4; ++j)
                    acc[i][j] = __builtin_amdgcn_mfma_f32_16x16x32_bf16(ah[i], bl4[j], acc[i][j], 0, 0, 0);
            #pragma unroll
            for (int i = 0; i < 4; ++i)
                #pragma unroll
                for (int j = 0; j < 4; ++j)
                    acc[i][j] = __builtin_amdgcn_mfma_f32_16x16x32_bf16(al[i], bh4[j], acc[i][j], 0, 0, 0);
        }
        __syncthreads();
    }

    #pragma unroll
    for (int i = 0; i < 4; ++i) {
        #pragma unroll
        for (int j = 0; j < 4; ++j) {
            int cc = col0 + wc + j * 16 + lr;
            float bval = bias[cc];
            #pragma unroll
            for (int q = 0; q < 4; ++q) {
                int rr = row0 + wr + i * 16 + lk * 4 + q;
                int bb = rr >> 12, l = rr & (LPAD - 1);
                float val = acc[i][j][q] + bval;
                if (mode == 0) {
                    if (seg < 2) val *= mask[(size_t)bb * LPAD + l] * QKSCALE;
                    size_t oi = (((size_t)bb * NHEADS + (cc >> 6)) * LPAD + l) * DH + (cc & 63);
                    u16 hh2, ll2; split2(val, hh2, ll2);
                    PH[oi] = hh2;
                    PL[oi] = ll2;
                } else {
                    if (l < S_ORIG)
                        outF[((size_t)bb * S_ORIG + l) * HIDDEN + cc] = val;
                }
            }
        }
    }
}

// ---------------------------------------------------------------------------
// Landmarks from Q/K pairs. Emits fp32 QL/KL and QL pairs. grid (128,32), 64t.
// ---------------------------------------------------------------------------
__global__ void k_landmarks(const u16* __restrict__ QPH, const u16* __restrict__ QPL,
                            const u16* __restrict__ KPH, const u16* __restrict__ KPL,
                            float* __restrict__ QL, float* __restrict__ KL,
                            u16* __restrict__ QLPH, u16* __restrict__ QLPL) {
    int n = blockIdx.x, bh = blockIdx.y, d = threadIdx.x;
    size_t base = ((size_t)bh * LPAD + n * 32) * DH + d;
    float sq = 0.f, sk = 0.f;
    #pragma unroll
    for (int s = 0; s < 32; ++s) {
        size_t a = base + (size_t)s * DH;
        sq += bf16f(QPH[a]) + bf16f(QPL[a]);
        sk += bf16f(KPH[a]) + bf16f(KPL[a]);
    }
    float ql = sq * (1.f / 32.f), kl = sk * (1.f / 32.f);
    size_t oi = ((size_t)bh * NLM + n) * DH + d;
    QL[oi] = ql;
    KL[oi] = kl;
    u16 hh2, ll2; split2(ql, hh2, ll2);
    QLPH[oi] = hh2;
    QLPL[oi] = ll2;
}

// ---------------------------------------------------------------------------
// Fused: K2 = softmax(QL @ KL^T)  AND  VA = V0 = K2^T / denom.
// grid (1, 32), 256 threads.
// ---------------------------------------------------------------------------
__global__ __launch_bounds__(256) void k_qlk_v0(const float* __restrict__ QLb,
                                                const float* __restrict__ Bsrc,
                                                float* __restrict__ K2out,
                                                float* __restrict__ VA) {
    __shared__ float Qt[64][132];
    __shared__ float Bt[64][132];
    __shared__ float redx[256];
    int tid = threadIdx.x;
    int tx = tid & 15, ty = tid >> 4;
    int bh = blockIdx.y;
    const float* QLp = QLb + (size_t)bh * NLM * DH;
    const float* Bp = Bsrc + (size_t)bh * NLM * DH;

    #pragma unroll
    for (int q = 0; q < 8; ++q) {
        int idx = tid + q * 256;
        int r = idx >> 4, d4 = idx & 15;
        float4 v = *(const float4*)(QLp + (size_t)r * DH + d4 * 4);
        Qt[d4 * 4 + 0][r] = v.x; Qt[d4 * 4 + 1][r] = v.y;
        Qt[d4 * 4 + 2][r] = v.z; Qt[d4 * 4 + 3][r] = v.w;
        float4 w = *(const float4*)(Bp + (size_t)r * DH + d4 * 4);
        Bt[d4 * 4 + 0][r] = w.x; Bt[d4 * 4 + 1][r] = w.y;
        Bt[d4 * 4 + 2][r] = w.z; Bt[d4 * 4 + 3][r] = w.w;
    }
    __syncthreads();

    float acc[8][8];
    #pragma unroll
    for (int i = 0; i < 8; ++i)
        #pragma unroll
        for (int j = 0; j < 8; ++j) acc[i][j] = 0.f;

    #pragma unroll
    for (int k = 0; k < 64; ++k) {
        float av[8], bv[8];
        float4 t0 = *(const float4*)&Qt[k][ty * 4];
        float4 t1 = *(const float4*)&Qt[k][64 + ty * 4];
        float4 t2 = *(const float4*)&Bt[k][tx * 4];
        float4 t3 = *(const float4*)&Bt[k][64 + tx * 4];
        av[0]=t0.x; av[1]=t0.y; av[2]=t0.z; av[3]=t0.w;
        av[4]=t1.x; av[5]=t1.y; av[6]=t1.z; av[7]=t1.w;
        bv[0]=t2.x; bv[1]=t2.y; bv[2]=t2.z; bv[3]=t2.w;
        bv[4]=t3.x; bv[5]=t3.y; bv[6]=t3.z; bv[7]=t3.w;
        #pragma unroll
        for (int i = 0; i < 8; ++i)
            #pragma unroll
            for (int j = 0; j < 8; ++j)
                acc[i][j] = fmaf(av[i], bv[j], acc[i][j]);
    }

    // softmax (rows private to 16-lane tx groups)
    float m[8], s[8];
    #pragma unroll
    for (int i = 0; i < 8; ++i) {
        m[i] = acc[i][0];
        #pragma unroll
        for (int j = 1; j < 8; ++j) m[i] = fmaxf(m[i], acc[i][j]);
    }
    #pragma unroll
    for (int o = 8; o >= 1; o >>= 1)
        #pragma unroll
        for (int i = 0; i < 8; ++i) m[i] = fmaxf(m[i], __shfl_xor(m[i], o));
    #pragma unroll
    for (int i = 0; i < 8; ++i) {
        s[i] = 0.f;
        #pragma unroll
        for (int j = 0; j < 8; ++j) {
            acc[i][j] = expf(acc[i][j] - m[i]);
            s[i] += acc[i][j];
        }
    }
    #pragma unroll
    for (int o = 8; o >= 1; o >>= 1)
        #pragma unroll
        for (int i = 0; i < 8; ++i) s[i] += __shfl_xor(s[i], o);
    #pragma unroll
    for (int i = 0; i < 8; ++i) {
        float inv = 1.f / s[i];
        #pragma unroll
        for (int j = 0; j < 8; ++j) acc[i][j] *= inv;
    }

    // write K2 (row-major, probs)
    #pragma unroll
    for (int i = 0; i < 8; ++i) {
        int r = (i >> 2) * 64 + ty * 4 + (i & 3);
        #pragma unroll
        for (int jh = 0; jh < 2; ++jh) {
            int c = jh * 64 + tx * 4;
            float4 res;
            res.x = acc[i][jh * 4 + 0]; res.y = acc[i][jh * 4 + 1];
            res.z = acc[i][jh * 4 + 2]; res.w = acc[i][jh * 4 + 3];
            *(float4*)(K2out + ((size_t)bh * NLM + r) * NLM + c) = res;
        }
    }

    // ---- denom: max row-sum (probs >= 0) ----
    float rmax = 0.f;
    #pragma unroll
    for (int i = 0; i < 8; ++i) {
        float rs = 0.f;
        #pragma unroll
        for (int j = 0; j < 8; ++j) rs += acc[i][j];
        rs += __shfl_xor(rs, 1);
        rs += __shfl_xor(rs, 2);
        rs += __shfl_xor(rs, 4);
        rs += __shfl_xor(rs, 8);
        rmax = fmaxf(rmax, rs);
    }
    redx[tid] = rmax;
    __syncthreads();
    for (int st = 128; st > 0; st >>= 1) {
        if (tid < st) redx[tid] = fmaxf(redx[tid], redx[tid + st]);
        __syncthreads();
    }
    float rmax_blk = redx[0];
    __syncthreads();

    // ---- max col-sum (partials via LDS, reuse Qt) ----
    float* colbuf = &Qt[0][0];
    #pragma unroll
    for (int j = 0; j < 8; ++j) {
        int c = (j >> 2) * 64 + tx * 4 + (j & 3);
        float cp = 0.f;
        #pragma unroll
        for (int i = 0; i < 8; ++i) cp += acc[i][j];
        colbuf[ty * 128 + c] = cp;
    }
    __syncthreads();
    float cs = 0.f;
    if (tid < 128) {
        #pragma unroll
        for (int t2 = 0; t2 < 16; ++t2) cs += colbuf[t2 * 128 + tid];
    }
    redx[tid] = cs;
    __syncthreads();
    for (int st = 128; st > 0; st >>= 1) {
        if (tid < st) redx[tid] = fmaxf(redx[tid], redx[tid + st]);
        __syncthreads();
    }
    float invden = 1.f / (rmax_blk * redx[0]);

    // ---- VA = K2^T * invden (transposed scalar writes) ----
    float* VAp = VA + (size_t)bh * NLM * NLM;
    #pragma unroll
    for (int i = 0; i < 8; ++i) {
        int r = (i >> 2) * 64 + ty * 4 + (i & 3);
        #pragma unroll
        for (int j = 0; j < 8; ++j) {
            int c = (j >> 2) * 64 + tx * 4 + (j & 3);
            VAp[(size_t)c * NLM + r] = acc[i][j] * invden;
        }
    }
}

// ---------------------------------------------------------------------------
// Batched matmul: C = alpha*(A@B) + sI  (A 128x128, B 128xN). fp32 VALU.
// 32x32 tiles, grid (N/32, 4, 32) -> fills all CUs per step.
// ---------------------------------------------------------------------------
__global__ __launch_bounds__(256) void k_bmm(const float* __restrict__ Ab,
                                             const float* __restrict__ Bb,
                                             float* __restrict__ Cb,
                                             float* __restrict__ C2b,
                                             int N, float alpha, float sI,
                                             float alpha2, float sI2) {
    __shared__ float At[128][36];
    __shared__ float Bs[128][36];
    int tid = threadIdx.x;
    int tx = tid & 15, ty = tid >> 4;
    int bh = blockIdx.z;
    int r0 = blockIdx.y * 32, c0 = blockIdx.x * 32;
    const float* A = Ab + (size_t)bh * NLM * NLM;
    const float* Bm = Bb + (size_t)bh * NLM * N;

    #pragma unroll
    for (int q = 0; q < 4; ++q) {
        int idx = tid + q * 256;
        int r = idx >> 5, k4 = idx & 31;
        float4 v = *(const float4*)(A + (size_t)(r0 + r) * NLM + k4 * 4);
        At[k4 * 4 + 0][r] = v.x; At[k4 * 4 + 1][r] = v.y;
        At[k4 * 4 + 2][r] = v.z; At[k4 * 4 + 3][r] = v.w;
        int bk = idx >> 3, c4 = idx & 7;
        float4 w = *(const float4*)(Bm + (size_t)bk * N + c0 + c4 * 4);
        *(float4*)&Bs[bk][c4 * 4] = w;
    }
    __syncthreads();

    float acc[2][2] = {};
    #pragma unroll 8
    for (int k = 0; k < 128; ++k) {
        float2 a2 = *(const float2*)&At[k][ty * 2];
        float2 b2 = *(const float2*)&Bs[k][tx * 2];
        acc[0][0] = fmaf(a2.x, b2.x, acc[0][0]);
        acc[0][1] = fmaf(a2.x, b2.y, acc[0][1]);
        acc[1][0] = fmaf(a2.y, b2.x, acc[1][0]);
        acc[1][1] = fmaf(a2.y, b2.y, acc[1][1]);
    }

    float* C = Cb + (size_t)bh * NLM * N;
    float* C2 = C2b ? (C2b + (size_t)bh * NLM * N) : nullptr;
    #pragma unroll
    for (int i = 0; i < 2; ++i) {
        int gr = r0 + ty * 2 + i;
        #pragma unroll
        for (int j = 0; j < 2; ++j) {
            int gc = c0 + tx * 2 + j;
            float idadd = (gr == gc) ? 1.f : 0.f;
            C[(size_t)gr * N + gc] = alpha * acc[i][j] + sI * idadd;
            if (C2) C2[(size_t)gr * N + gc] = alpha2 * acc[i][j] + sI2 * idadd;
        }
    }
}

// ---------------------------------------------------------------------------
// Flash-style fused kernel_3 path, pair inputs. Grid (8 sp, 2 qh, 32 bh).
// KV-tile = 64, LDS 64 KB (2 WG/CU).
// ---------------------------------------------------------------------------
__global__ __launch_bounds__(256) void k_flashk3(const u16* __restrict__ QLPH,
                                                 const u16* __restrict__ QLPL,
                                                 const u16* __restrict__ KPH,
                                                 const u16* __restrict__ KPL,
                                                 const u16* __restrict__ VPH,
                                                 const u16* __restrict__ VPL,
                                                 const float* __restrict__ mask,
                                                 float* __restrict__ PO,
                                                 float* __restrict__ ML) {
    __shared__ u16 lds[32768];        // 64 KB
    u16* QLh = lds;                   // 64x64 each plane (4096 u16)
    u16* QLl = lds + 4096;
    u16* Kh  = lds + 8192;            // 64x64
    u16* Kl  = lds + 12288;
    u16* Vth = lds + 16384;           // 64x64 (V transposed [d][n])
    u16* Vtl = lds + 20480;
    u16* Ph  = lds + 24576;           // 64x64
    u16* Pl  = lds + 28672;

    int tid = threadIdx.x;
    int lane = tid & 63, wv = tid >> 6;
    int lr = lane & 15, lk = lane >> 4;
    int sp = blockIdx.x, qh = blockIdx.y, bh = blockIdx.z;
    int b = bh >> 4;
    int q0 = qh * 64;
    int wr16 = wv * 16;               // wave's 16 rows (local 0..63)

    // ---- stage QL pairs via global_load_lds (inverse-swizzled source) ----
    #pragma unroll
    for (int q = 0; q < 2; ++q) {
        int idx = tid + q * 256;
        int r = idx >> 3, sc = idx & 7;
        int csrc = (sc ^ (r & 7)) * 8;
        size_t g = ((size_t)bh * NLM + q0 + r) * DH + csrc;
        __builtin_amdgcn_global_load_lds(
            (const __attribute__((address_space(1))) void*)(QLPH + g),
            (__attribute__((address_space(3))) void*)(&QLh[idx * 8]), 16, 0, 0);
        __builtin_amdgcn_global_load_lds(
            (const __attribute__((address_space(1))) void*)(QLPL + g),
            (__attribute__((address_space(3))) void*)(&QLl[idx * 8]), 16, 0, 0);
    }

    float m_run[4] = {-1e30f, -1e30f, -1e30f, -1e30f};
    float l_run[4] = {0.f, 0.f, 0.f, 0.f};
    f32x4 t5[4] = {};                 // rows wr16+lk*4+q, cols d=j*16+lr

    for (int t = 0; t < 8; ++t) {
        int kt0 = sp * 512 + t * 64;
        // ---- stage K pairs via global_load_lds (64 rows) ----
        #pragma unroll
        for (int q = 0; q < 2; ++q) {
            int idx = tid + q * 256;
            int r = idx >> 3, sc = idx & 7;
            int csrc = (sc ^ (r & 7)) * 8;
            size_t g = ((size_t)bh * LPAD + kt0 + r) * DH + csrc;
            __builtin_amdgcn_global_load_lds(
                (const __attribute__((address_space(1))) void*)(KPH + g),
                (__attribute__((address_space(3))) void*)(&Kh[idx * 8]), 16, 0, 0);
            __builtin_amdgcn_global_load_lds(
                (const __attribute__((address_space(1))) void*)(KPL + g),
                (__attribute__((address_space(3))) void*)(&Kl[idx * 8]), 16, 0, 0);
        }
        // ---- stage V transposed (pairs; row-fixed contiguous writes) ----
        #pragma unroll
        for (int q = 0; q < 4; ++q) {
            int idx = tid + q * 256;
            int n = idx & 63, dg = idx >> 6;      // dg 0..15
            int d4 = dg * 4;
            size_t g = ((size_t)bh * LPAD + kt0 + n) * DH + d4;
            ushort4 h4 = *(const ushort4*)(VPH + g);
            ushort4 l4 = *(const ushort4*)(VPL + g);
            #pragma unroll
            for (int e = 0; e < 4; ++e) {
                Vth[IDX64(d4 + e, n)] = (&h4.x)[e];
                Vtl[IDX64(d4 + e, n)] = (&l4.x)[e];
            }
        }
        __syncthreads();

        // ---- S = QL @ K^T : wave 16 rows x 64 cols (t4[4]) ----
        f32x4 t4[4] = {};
        #pragma unroll
        for (int tt = 0; tt < 3; ++tt) {
            const u16* Xs = (tt == 2) ? QLl : QLh;
            const u16* Ys = (tt == 1) ? Kl : Kh;
            #pragma unroll
            for (int kc = 0; kc < 2; ++kc) {
                s16x8 a = *(const s16x8*)&Xs[IDX64(wr16 + lr, kc * 32 + lk * 8)];
                s16x8 bfr[4];
                #pragma unroll
                for (int j = 0; j < 4; ++j)
                    bfr[j] = *(const s16x8*)&Ys[IDX64(j * 16 + lr, kc * 32 + lk * 8)];
                #pragma unroll
                for (int j = 0; j < 4; ++j)
                    t4[j] = __builtin_amdgcn_mfma_f32_16x16x32_bf16(a, bfr[j], t4[j], 0, 0, 0);
            }
        }

        // ---- mask penalty ----
        #pragma unroll
        for (int j = 0; j < 4; ++j) {
            float pen = 1e9f * (1.f - mask[(size_t)b * LPAD + kt0 + j * 16 + lr]);
            #pragma unroll
            for (int q = 0; q < 4; ++q) t4[j][q] -= pen;
        }

        // ---- online softmax per row (16-lane group reduce over 64 cols) ----
        float alpha[4];
        #pragma unroll
        for (int q = 0; q < 4; ++q) {
            float tm = t4[0][q];
            #pragma unroll
            for (int j = 1; j < 4; ++j) tm = fmaxf(tm, t4[j][q]);
            tm = fmaxf(tm, __shfl_xor(tm, 1));
            tm = fmaxf(tm, __shfl_xor(tm, 2));
            tm = fmaxf(tm, __shfl_xor(tm, 4));
            tm = fmaxf(tm, __shfl_xor(tm, 8));
            float mn = fmaxf(m_run[q], tm);
            float al = expf(m_run[q] - mn);
            float s = 0.f;
            #pragma unroll
            for (int j = 0; j < 4; ++j) {
                t4[j][q] = expf(t4[j][q] - mn);
                s += t4[j][q];
            }
            s += __shfl_xor(s, 1);
            s += __shfl_xor(s, 2);
            s += __shfl_xor(s, 4);
            s += __shfl_xor(s, 8);
            l_run[q] = l_run[q] * al + s;
            m_run[q] = mn;
            alpha[q] = al;
        }
        // rescale O accumulator
        #pragma unroll
        for (int j = 0; j < 4; ++j)
            #pragma unroll
            for (int q = 0; q < 4; ++q) t5[j][q] *= alpha[q];

        // ---- write P pair (wave-private rows; no barrier needed before PV) ----
        #pragma unroll
        for (int j = 0; j < 4; ++j) {
            int col = j * 16 + lr;
            #pragma unroll
            for (int q = 0; q < 4; ++q) {
                int row = wr16 + lk * 4 + q;
                u16 hh2, ll2; split2(t4[j][q], hh2, ll2);
                Ph[IDX64(row, col)] = hh2;
                Pl[IDX64(row, col)] = ll2;
            }
        }

        // ---- O += P @ V (K=64, 3 split terms): wave 16 rows x 64 cols ----
        #pragma unroll
        for (int tt = 0; tt < 3; ++tt) {
            const u16* Xs = (tt == 2) ? Pl : Ph;
            const u16* Ys = (tt == 1) ? Vtl : Vth;
            #pragma unroll
            for (int kc = 0; kc < 2; ++kc) {
                s16x8 a = *(const s16x8*)&Xs[IDX64(wr16 + lr, kc * 32 + lk * 8)];
                s16x8 bfr[4];
                #pragma unroll
                for (int j = 0; j < 4; ++j)
                    bfr[j] = *(const s16x8*)&Ys[IDX64(j * 16 + lr, kc * 32 + lk * 8)];
                #pragma unroll
                for (int j = 0; j < 4; ++j)
                    t5[j] = __builtin_amdgcn_mfma_f32_16x16x32_bf16(a, bfr[j], t5[j], 0, 0, 0);
            }
        }
        __syncthreads();   // protect K/V/P before next tile's staging
    }

    // ---- emit partials ----
    size_t pb = (size_t)(bh * 16 + qh * 8 + sp) * 64;
    #pragma unroll
    for (int j = 0; j < 4; ++j) {
        int d = j * 16 + lr;
        #pragma unroll
        for (int q = 0; q < 4; ++q) {
            int row = wr16 + lk * 4 + q;
            PO[(pb + row) * 64 + d] = t5[j][q];
        }
    }
    if (lr == 0) {
        #pragma unroll
        for (int q = 0; q < 4; ++q) {
            int row = wr16 + lk * 4 + q;
            ML[(pb + row) * 2 + 0] = m_run[q];
            ML[(pb + row) * 2 + 1] = l_run[q];
        }
    }
}

// Combine 8 split-K partials -> K3V[bh][128][64].
__global__ void k_flash_combine(const float* __restrict__ PO,
                                const float* __restrict__ ML,
                                float* __restrict__ K3V) {
    int idx = blockIdx.x * 256 + threadIdx.x;
    int bh = idx >> 13, rem = idx & 8191;
    int g = rem >> 6, d = rem & 63;
    int qh = g >> 6, rl = g & 63;
    size_t rb = (size_t)(bh * 16 + qh * 8) * 64 + rl;
    float mstar = -1e30f;
    #pragma unroll
    for (int sp = 0; sp < 8; ++sp)
        mstar = fmaxf(mstar, ML[(rb + (size_t)sp * 64) * 2]);
    float osum = 0.f, lsum = 0.f;
    #pragma unroll
    for (int sp = 0; sp < 8; ++sp) {
        size_t r = rb + (size_t)sp * 64;
        float wgt = expf(ML[r * 2] - mstar);
        osum += wgt * PO[r * 64 + d];
        lsum += wgt * ML[r * 2 + 1];
    }
    K3V[idx] = osum / lsum;
}

// ---------------------------------------------------------------------------
// kernel_1 fused via split-bf16 MFMA: ATTN = softmax(Q_tile @ KL^T) @ MM.
// Q staged from pairs via global_load_lds (async, no VALU split).
// ---------------------------------------------------------------------------
__global__ __launch_bounds__(256) void k_attn(const u16* __restrict__ QPH,
                                              const u16* __restrict__ QPL,
                                              const float* __restrict__ KLb,
                                              const float* __restrict__ MMb,
                                              u16* __restrict__ ATH,
                                              u16* __restrict__ ATL) {
    __shared__ u16 lds[49152];
    u16* Qh  = lds;               // 8192 (128x64)
    u16* Ql  = lds + 8192;
    u16* KLh = lds + 16384;
    u16* KLl = lds + 24576;
    u16* Ph  = lds;               // 16384 (128x128), overwrites Q/KL
    u16* Pl  = lds + 16384;
    u16* Mth = lds + 32768;       // 8192 (64x128)
    u16* Mtl = lds + 40960;

    int tid = threadIdx.x;
    int lane = tid & 63, wv = tid >> 6;
    int lr = lane & 15, lk = lane >> 4;
    int l0 = blockIdx.x * 128, bh = blockIdx.y;
    int b = bh >> 4, hh = bh & 15;
    int wrA = wv * 32;            // wave's 32 rows (both matmuls)

    // ---- stage Q pairs via global_load_lds (inverse-swizzled source) ----
    #pragma unroll
    for (int q = 0; q < 4; ++q) {
        int idx = tid + q * 256;
        int r = idx >> 3, sc = idx & 7;
        int csrc = (sc ^ (r & 7)) * 8;
        size_t g = ((size_t)bh * LPAD + l0 + r) * DH + csrc;
        __builtin_amdgcn_global_load_lds(
            (const __attribute__((address_space(1))) void*)(QPH + g),
            (__attribute__((address_space(3))) void*)(&Qh[idx * 8]), 16, 0, 0);
        __builtin_amdgcn_global_load_lds(
            (const __attribute__((address_space(1))) void*)(QPL + g),
            (__attribute__((address_space(3))) void*)(&Ql[idx * 8]), 16, 0, 0);
    }
    // ---- stage KL (fp32 -> split, IDX64) ----
    #pragma unroll
    for (int q = 0; q < 4; ++q) {
        int idx = tid + q * 256;
        int r = idx >> 3, c8 = (idx & 7) * 8;
        float4 w0 = *(const float4*)(KLb + ((size_t)bh * NLM + r) * DH + c8);
        float4 w1 = *(const float4*)(KLb + ((size_t)bh * NLM + r) * DH + c8 + 4);
        float ys[8] = {w0.x, w0.y, w0.z, w0.w, w1.x, w1.y, w1.z, w1.w};
        s16x8 h8, l8;
        #pragma unroll
        for (int e = 0; e < 8; ++e) {
            u16 hh2, ll2; split2(ys[e], hh2, ll2);
            h8[e] = (short)hh2; l8[e] = (short)ll2;
        }
        *(s16x8*)&KLh[IDX64(r, c8)] = h8;
        *(s16x8*)&KLl[IDX64(r, c8)] = l8;
    }
    // ---- stage MM transposed (split, IDX128) ----
    #pragma unroll
    for (int q = 0; q < 8; ++q) {
        int idx = tid + q * 256;
        int n = idx >> 4, d4 = (idx & 15) * 4;
        float4 v = *(const float4*)(MMb + ((size_t)bh * NLM + n) * DH + d4);
        float xs[4] = {v.x, v.y, v.z, v.w};
        #pragma unroll
        for (int e = 0; e < 4; ++e) {
            u16 hh2, ll2; split2(xs[e], hh2, ll2);
            Mth[IDX128(d4 + e, n)] = hh2;
            Mtl[IDX128(d4 + e, n)] = ll2;
        }
    }
    __syncthreads();

    // ---- S = Q @ KL^T : wave owns 32 rows x 128 cols (t4[2][8]) ----
    f32x4 t4[2][8] = {};
    #pragma unroll
    for (int t = 0; t < 3; ++t) {
        const u16* Xs = (t == 2) ? Ql : Qh;
        const u16* Ys = (t == 1) ? KLl : KLh;
        #pragma unroll
        for (int kc = 0; kc < 2; ++kc) {
            s16x8 a[2], bfr[8];
            #pragma unroll
            for (int i = 0; i < 2; ++i)
                a[i] = *(const s16x8*)&Xs[IDX64(wrA + i * 16 + lr, kc * 32 + lk * 8)];
            #pragma unroll
            for (int j = 0; j < 8; ++j)
                bfr[j] = *(const s16x8*)&Ys[IDX64(j * 16 + lr, kc * 32 + lk * 8)];
            #pragma unroll
            for (int i = 0; i < 2; ++i)
                #pragma unroll
                for (int j = 0; j < 8; ++j)
                    t4[i][j] = __builtin_amdgcn_mfma_f32_16x16x32_bf16(a[i], bfr[j], t4[i][j], 0, 0, 0);
        }
    }

    // ---- row softmax ----
    #pragma unroll
    for (int i = 0; i < 2; ++i)
        #pragma unroll
        for (int q = 0; q < 4; ++q) {
            float m = t4[i][0][q];
            #pragma unroll
            for (int j = 1; j < 8; ++j) m = fmaxf(m, t4[i][j][q]);
            m = fmaxf(m, __shfl_xor(m, 1));
            m = fmaxf(m, __shfl_xor(m, 2));
            m = fmaxf(m, __shfl_xor(m, 4));
            m = fmaxf(m, __shfl_xor(m, 8));
            float s = 0.f;
            #pragma unroll
            for (int j = 0; j < 8; ++j) {
                t4[i][j][q] = expf(t4[i][j][q] - m);
                s += t4[i][j][q];
            }
            s += __shfl_xor(s, 1);
            s += __shfl_xor(s, 2);
            s += __shfl_xor(s, 4);
            s += __shfl_xor(s, 8);
            float inv = 1.f / s;
            #pragma unroll
            for (int j = 0; j < 8; ++j) t4[i][j][q] *= inv;
        }

    __syncthreads();   // Q/KL reads done; safe to overwrite with P
    #pragma unroll
    for (int i = 0; i < 2; ++i)
        #pragma unroll
        for (int j = 0; j < 8; ++j) {
            int col = j * 16 + lr;
            #pragma unroll
            for (int q = 0; q < 4; ++q) {
                int row = wrA + i * 16 + lk * 4 + q;
                u16 hh2, ll2; split2(t4[i][j][q], hh2, ll2);
                Ph[IDX128(row, col)] = hh2;
                Pl[IDX128(row, col)] = ll2;
            }
        }
    __syncthreads();

    // ---- O = P @ MM (K=128, 3 split terms) ----
    f32x4 t5[2][4] = {};
    #pragma unroll
    for (int t = 0; t < 3; ++t) {
        const u16* Xs = (t == 2) ? Pl : Ph;
        const u16* Ys = (t == 1) ? Mtl : Mth;
        #pragma unroll
        for (int kc = 0; kc < 4; ++kc) {
            s16x8 a[2], bfr[4];
            #pragma unroll
            for (int i = 0; i < 2; ++i)
                a[i] = *(const s16x8*)&Xs[IDX128(wrA + i * 16 + lr, kc * 32 + lk * 8)];
            #pragma unroll
            for (int j = 0; j < 4; ++j)
                bfr[j] = *(const s16x8*)&Ys[IDX128(j * 16 + lr, kc * 32 + lk * 8)];
            #pragma unroll
            for (int i = 0; i < 2; ++i)
                #pragma unroll
                for (int j = 0; j < 4; ++j)
                    t5[i][j] = __builtin_amdgcn_mfma_f32_16x16x32_bf16(a[i], bfr[j], t5[i][j], 0, 0, 0);
        }
    }

    // ---- epilogue: split O -> ATH/ATL ----
    #pragma unroll
    for (int i = 0; i < 2; ++i)
        #pragma unroll
        for (int j = 0; j < 4; ++j) {
            int d = j * 16 + lr;
            #pragma unroll
            for (int q = 0; q < 4; ++q) {
                int l = l0 + wrA + i * 16 + lk * 4 + q;
                size_t base = ((size_t)b * LPAD + l) * HIDDEN + hh * DH + d;
                u16 hh2, ll2; split2(t5[i][j][q], hh2, ll2);
                ATH[base] = hh2;
                ATL[base] = ll2;
            }
        }
}

// ---------------------------------------------------------------------------
extern "C" void kernel_launch(void* const* d_in, const int* in_sizes, int n_in,
                              void* d_out, int out_size, void* d_ws, size_t ws_size,
                              hipStream_t stream) {
    (void)in_sizes; (void)n_in; (void)out_size; (void)ws_size;
    const float* X    = (const float*)d_in[0];
    const float* mask = (const float*)d_in[1];
    const float* Wq   = (const float*)d_in[2];
    const float* bq   = (const float*)d_in[3];
    const float* Wk   = (const float*)d_in[4];
    const float* bk   = (const float*)d_in[5];
    const float* Wv   = (const float*)d_in[6];
    const float* bv   = (const float*)d_in[7];
    const float* Wo   = (const float*)d_in[8];
    const float* bo   = (const float*)d_in[9];
    float* out = (float*)d_out;
    float* w = (float*)d_ws;

    size_t o = 0;
    u16* WQH = (u16*)(w + o); o += (size_t)HIDDEN * HIDDEN / 2;
    u16* WQL = (u16*)(w + o); o += (size_t)HIDDEN * HIDDEN / 2;
    u16* WKH = (u16*)(w + o); o += (size_t)HIDDEN * HIDDEN / 2;
    u16* WKL = (u16*)(w + o); o += (size_t)HIDDEN * HIDDEN / 2;
    u16* WVH = (u16*)(w + o); o += (size_t)HIDDEN * HIDDEN / 2;
    u16* WVL = (u16*)(w + o); o += (size_t)HIDDEN * HIDDEN / 2;
    u16* WOH = (u16*)(w + o); o += (size_t)HIDDEN * HIDDEN / 2;
    u16* WOL = (u16*)(w + o); o += (size_t)HIDDEN * HIDDEN / 2;
    float* Q   = w + o; o += (size_t)BHT * LPAD * DH;   // Q pairs
    float* K   = w + o; o += (size_t)BHT * LPAD * DH;   // K pairs
    float* V   = w + o; o += (size_t)BHT * LPAD * DH;   // V pairs
    float* QL  = w + o; o += (size_t)BHT * NLM * DH;
    float* KL  = w + o; o += (size_t)BHT * NLM * DH;
    float* K2  = w + o; o += (size_t)BHT * NLM * NLM;
    float* VA  = w + o; o += (size_t)BHT * NLM * NLM;
    float* VB  = w + o; o += (size_t)BHT * NLM * NLM;
    float* KV  = w + o; o += (size_t)BHT * NLM * NLM;
    float* P1  = w + o; o += (size_t)BHT * NLM * NLM;
    float* T3  = w + o; o += (size_t)BHT * NLM * NLM;
    float* PK  = w + o; o += (size_t)BHT * 16 * NLM * DH;
    float* K3V = w + o; o += (size_t)BHT * NLM * DH;
    float* MM  = w + o; o += (size_t)BHT * NLM * DH;
    float* SC  = w + o; o += (size_t)BHT * NLM * LPAD;

    // Q/K/V buffers hold bf16 pairs (exact fit: fp32 size == 2 u16 planes)
    u16* QPH = (u16*)Q;
    u16* QPL = QPH + (size_t)BHT * LPAD * DH;
    u16* KPH = (u16*)K;
    u16* KPL = KPH + (size_t)BHT * LPAD * DH;
    u16* VPH = (u16*)V;
    u16* VPL = VPH + (size_t)BHT * LPAD * DH;

    // Flash partials live in PK (PO 8.4 MB + ML 0.26 MB < 16.8 MB).
    float* PO = PK;
    float* ML = PK + (size_t)BHT * 16 * 64 * 64;

    // Time-shared aliases of the SC region (disjoint live windows):
    u16* XH  = (u16*)SC;
    u16* XL  = XH + (size_t)2 * LPAD * HIDDEN;
    u16* ATH = (u16*)SC;
    u16* ATL = ATH + (size_t)2 * LPAD * HIDDEN;
    // QL pairs: placed far past XH/XL and ATH/ATL regions within SC.
    u16* QLPH = (u16*)SC + (size_t)32 * 1024 * 1024;
    u16* QLPL = QLPH + (size_t)BHT * NLM * DH;

    k_split_x<<<8192, 256, 0, stream>>>(X, XH, XL);
    k_split_w4<<<dim3(1024, 4), 256, 0, stream>>>(Wq, Wk, Wv, Wo,
        WQH, WQL, WKH, WKL, WVH, WVL, WOH, WOL);

    // Fused QKV projection: one launch, grid (64, 24). All outputs pairs.
    k_gemm_bf16<<<dim3(64, 24), 256, 0, stream>>>(
        XH, XL, WQH, WQL, WKH, WKL, WVH, WVL, bq, bk, bv, mask,
        QPH, QPL, KPH, KPL, VPH, VPL, nullptr, 0);

    k_landmarks<<<dim3(NLM, BHT), 64, 0, stream>>>(QPH, QPL, KPH, KPL, QL, KL, QLPH, QLPL);

    // K2 softmax + V0/denom fused
    k_qlk_v0<<<dim3(1, BHT), 256, 0, stream>>>(QL, KL, K2, VA);

    k_flashk3<<<dim3(8, 2, BHT), 256, 0, stream>>>(QLPH, QLPL, KPH, KPL, VPH, VPL, mask, PO, ML);
    k_flash_combine<<<(BHT * NLM * DH) / 256, 256, 0, stream>>>(PO, ML, K3V);

    float* cur = VA;
    float* nxt = VB;
    for (int it = 0; it < 6; ++it) {
        k_bmm<<<dim3(4, 4, BHT), 256, 0, stream>>>(K2, cur, KV, P1, NLM, 1.f, 0.f, -1.f, 7.f);
        k_bmm<<<dim3(4, 4, BHT), 256, 0, stream>>>(KV, P1, T3, nullptr, NLM, -1.f, 15.f, 0.f, 0.f);
        k_bmm<<<dim3(4, 4, BHT), 256, 0, stream>>>(KV, T3, P1, nullptr, NLM, -1.f, 13.f, 0.f, 0.f);
        k_bmm<<<dim3(4, 4, BHT), 256, 0, stream>>>(cur, P1, nxt, nullptr, NLM, 0.25f, 0.f, 0.f, 0.f);
        float* t = cur; cur = nxt; nxt = t;
    }

    k_bmm<<<dim3(2, 4, BHT), 256, 0, stream>>>(cur, K3V, MM, nullptr, DH, 1.f, 0.f, 0.f, 0.f);

    k_attn<<<dim3(32, BHT), 256, 0, stream>>>(QPH, QPL, KL, MM, ATH, ATL);

    // Final projection: grid (64, 8), mode 1 (B0 slot = Wo).
    k_gemm_bf16<<<dim3(64, 8), 256, 0, stream>>>(
        ATH, ATL, WOH, WOL, nullptr, nullptr, nullptr, nullptr, bo, nullptr,
        nullptr, nullptr, nullptr, nullptr, nullptr, nullptr, nullptr, nullptr, out, 1);
}